// Round 17
// baseline (443.754 us; speedup 1.0000x reference)
//
#include <hip/hip_runtime.h>
#include <hip/hip_bf16.h>

typedef unsigned short u16;
typedef unsigned char  u8;
typedef unsigned int   u32;
typedef unsigned long long u64;

typedef short bf16x8 __attribute__((ext_vector_type(8)));
typedef float f32x4  __attribute__((ext_vector_type(4)));
typedef float f32x16 __attribute__((ext_vector_type(16)));

#define DEVI static __device__ __forceinline__

// ---- problem geometry ----
constexpr int B  = 2;
constexpr int C0 = 4,   D0 = 40, H0 = 256, W0 = 256;
constexpr int C1 = 32,  D1 = 20, H1 = 128, W1 = 128;
constexpr int C2 = 64;
constexpr int C3 = 128, D3 = 10, H3 = 64,  W3 = 64;
constexpr int S0 = D0 * H0 * W0;
constexpr int S1 = D1 * H1 * W1;             // 327,680
constexpr int S3 = D3 * H3 * W3;             // 40,960
constexpr int NV1 = B * S1;                  // 655,360
constexpr int NV3 = B * S3;                  // 81,920
constexpr int WP1 = W1 + 2;                  // padded x stride (130)
constexpr int NROW1 = B * D1 * H1;           // 5120 padded rows
constexpr int PVOX1 = NROW1 * WP1;           // 665,600 padded voxels
constexpr int RSTRIDE = 2080;                // conv1 staged row stride (bytes)

// ---- bf16 helpers ----
DEVI float b2f(u16 v) { return __uint_as_float(((u32)v) << 16); }
DEVI u16 f2b(float f) {
  u32 u = __float_as_uint(f);
  return (u16)((u + 0x7fffu + ((u >> 16) & 1u)) >> 16);
}
DEVI u32 pk2(float a, float b) { return (u32)f2b(a) | ((u32)f2b(b) << 16); }
DEVI void bf8_unpack(const uint4 u, float* f) {
  f[0] = b2f((u16)(u.x & 0xffffu)); f[1] = b2f((u16)(u.x >> 16));
  f[2] = b2f((u16)(u.y & 0xffffu)); f[3] = b2f((u16)(u.y >> 16));
  f[4] = b2f((u16)(u.z & 0xffffu)); f[5] = b2f((u16)(u.z >> 16));
  f[6] = b2f((u16)(u.w & 0xffffu)); f[7] = b2f((u16)(u.w >> 16));
}
DEVI float colred(float v) {   // sum over 16 lanes (bits 0..3)
  v += __shfl_xor(v, 1); v += __shfl_xor(v, 2);
  v += __shfl_xor(v, 4); v += __shfl_xor(v, 8);
  return v;
}
DEVI float colred32(float v) { // sum over 32 lanes (bits 0..4)
  v += __shfl_xor(v, 1); v += __shfl_xor(v, 2);
  v += __shfl_xor(v, 4); v += __shfl_xor(v, 8);
  v += __shfl_xor(v, 16);
  return v;
}
DEVI int xswz(int b, int n) {  // XCD-contiguous bijective swizzle (n % 8 == 0)
  const int c = n >> 3;
  return (b & 7) * c + (b >> 3);
}
DEVI void glds16(const void* g, void* l) {  // async global->LDS, 16B per lane
  __builtin_amdgcn_global_load_lds(
      (const __attribute__((address_space(1))) void*)g,
      (__attribute__((address_space(3))) void*)l, 16, 0, 0);
}

// ---- pre-pass: masked feature gather + f32->bf16 convert ----
__global__ __launch_bounds__(256) void sl_prepack(
    const float* __restrict__ feat, const int* __restrict__ act,
    u16* __restrict__ mfeat, u8* __restrict__ aflag) {
  const int i = blockIdx.x * 256 + threadIdx.x;   // < B*S0
  const int b = i / S0, sp = i - b * S0;
  u32 w0 = 0, w1 = 0; u8 fl = 0;
  if (act[i] == 0) {
    fl = 1;
    const size_t fb = (size_t)b * 4 * S0 + sp;
    w0 = pk2(feat[fb], feat[fb + S0]);
    w1 = pk2(feat[fb + 2 * (size_t)S0], feat[fb + 3 * (size_t)S0]);
  }
  *reinterpret_cast<uint2*>(mfeat + (size_t)i * 4) = uint2{w0, w1};
  aflag[i] = fl;
}

// ---- conv2 weight repack for 32x32x16 MFMA ----
// dst[((t*2+kk)*2+mh)*64 + l][j] = w2[mh*32+(l&31)][kk*16+(l>>5)*8+j][t]
__global__ __launch_bounds__(256) void sl_repackA2w(const float* __restrict__ src,
                                                    u16* __restrict__ dst) {
  const int idx = blockIdx.x * 256 + threadIdx.x;   // < 6912
  if (idx >= 6912) return;
  const int l = idx & 63;
  int r = idx >> 6;
  const int mh = r & 1;
  const int kk = (r >> 1) & 1;
  const int t = r >> 2;
  const int o = mh * 32 + (l & 31);
  const int i0 = kk * 16 + (l >> 5) * 8;
  u16 f[8];
#pragma unroll
  for (int j = 0; j < 8; ++j) f[j] = f2b(src[((size_t)o * 32 + i0 + j) * 27 + t]);
  *reinterpret_cast<uint4*>(dst + (size_t)idx * 8) = *reinterpret_cast<uint4*>(f);
}

// ---- weight repack, mb-major (conv3) ----
__global__ __launch_bounds__(256) void sl_repackA3(const float* __restrict__ src,
                                                   u16* __restrict__ dst) {
  const int total = 27 * 8 * 2 * 64;
  const int idx = blockIdx.x * 256 + threadIdx.x;
  if (idx >= total) return;
  const int l = idx & 63;
  int r = idx >> 6;
  const int kk = r % 2; r /= 2;
  const int mb = r % 8;
  const int t = r / 8;
  const int o = mb * 16 + (l & 15);
  const int i0 = kk * 32 + (l >> 4) * 8;
  u16 f[8];
#pragma unroll
  for (int j = 0; j < 8; ++j) f[j] = f2b(src[((size_t)o * 64 + i0 + j) * 27 + t]);
  *reinterpret_cast<uint4*>(dst + (size_t)idx * 8) = *reinterpret_cast<uint4*>(f);
}

// ---- conv1 weight repack: K = tap*4 + ic, padded to 128 ----
__global__ __launch_bounds__(256) void sl_repackA1(const float* __restrict__ src,
                                                   u16* __restrict__ dst) {
  const int idx = blockIdx.x * 256 + threadIdx.x;   // < 512
  if (idx >= 512) return;
  const int l = idx & 63;
  int r = idx >> 6;
  const int mb = r % 2;
  const int kk = r / 2;
  const int o = mb * 16 + (l & 15);
  u16 f[8];
#pragma unroll
  for (int j = 0; j < 8; ++j) {
    const int k = kk * 32 + (l >> 4) * 8 + j;
    const int t = k >> 2, ic = k & 3;
    f[j] = (t < 27) ? f2b(src[((size_t)o * 4 + ic) * 27 + t]) : (u16)0;
  }
  *reinterpret_cast<uint4*>(dst + (size_t)idx * 8) = *reinterpret_cast<uint4*>(f);
}

// ---- zero the x-halo columns of x1p ----
__global__ __launch_bounds__(256) void sl_halo1(u16* __restrict__ x1p) {
  const int i = blockIdx.x * 256 + threadIdx.x;
  if (i >= 2 * NROW1) return;
  const int r = i >> 1, side = i & 1;
  const size_t p = (size_t)r * WP1 + side * (WP1 - 1);
  const uint4 z4 = {0u, 0u, 0u, 0u};
  uint4* p1 = reinterpret_cast<uint4*>(x1p + p * 32);
#pragma unroll
  for (int j = 0; j < 4; ++j) p1[j] = z4;
}

// ---- conv1 via MFMA: glds-staged im2col; mask1 + BN1 partials; no atomics ----
__global__ __launch_bounds__(256) void sl_conv1_mfma(
    const u16* __restrict__ mfeat, const u8* __restrict__ aflag,
    const u16* __restrict__ wA, const u16* __restrict__ zbuf,
    u16* __restrict__ x1p, u8* __restrict__ mask1,
    float* __restrict__ part1, float* __restrict__ cnt1buf) {
  __shared__ __align__(16) char sfeat[10 * RSTRIDE];   // 20,800 B
  __shared__ __align__(16) u8 sflagP[9 * 256];         //  2,304 B
  __shared__ float smask[128];
  const int tid = threadIdx.x;
  const int row = xswz(blockIdx.x, NROW1);   // (b*D1+z)*H1 + y
  const int y = row & (H1 - 1);
  const int bz = row >> 7;
  const int z = bz % D1;
  const int b = bz / D1;
  const int wv = tid >> 6, ln = tid & 63;
  const uint4 z4 = {0u, 0u, 0u, 0u};
  if (tid < 18) {
    const int r = tid >> 1, side = tid & 1;
    *reinterpret_cast<uint4*>(&sfeat[r * RSTRIDE + side * 2064]) = z4;
  } else if (tid < 148) {
    const int idx = tid - 18;
    *reinterpret_cast<uint4*>(&sfeat[9 * RSTRIDE + idx * 16]) = z4;
  }
#pragma unroll
  for (int i = 0; i < 5; ++i) {
    const int h = i * 4 + wv;
    if (h < 18) {
      const int r9 = h >> 1, half = h & 1;
      const int zi = 2 * z + r9 / 3 - 1;
      const int yi = 2 * y + r9 % 3 - 1;
      const u16* src;
      if ((unsigned)zi < (unsigned)D0 && (unsigned)yi < (unsigned)H0)
        src = mfeat + ((size_t)(b * S0 + (zi * H0 + yi) * W0 + half * 128) + 2 * ln) * 4;
      else
        src = zbuf + ln * 8;
      glds16(src, &sfeat[r9 * RSTRIDE + 16 + half * 1024]);
    }
  }
  {
    const int r9 = tid >> 4, k = tid & 15;
    if (r9 < 9) {
      const int zi = 2 * z + r9 / 3 - 1;
      const int yi = 2 * y + r9 % 3 - 1;
      const void* src;
      if ((unsigned)zi < (unsigned)D0 && (unsigned)yi < (unsigned)H0)
        src = aflag + b * S0 + (zi * H0 + yi) * W0 + k * 16;
      else
        src = (const u8*)zbuf + ln * 16;
      glds16(src, &sflagP[wv * 1024]);
    }
  }
  __syncthreads();
  if (tid < 128) {
    bool any = false;
#pragma unroll
    for (int r9 = 0; r9 < 9; ++r9)
#pragma unroll
      for (int dx = 0; dx < 3; ++dx) {
        const int xi = 2 * tid + dx - 1;
        any |= (xi >= 0) && (sflagP[r9 * 256 + xi] != 0);
      }
    mask1[row * W1 + tid] = any ? (u8)1 : (u8)0;
    smask[tid] = any ? 1.f : 0.f;
    const u64 bal = __ballot(any);
    if ((tid & 63) == 0)
      cnt1buf[blockIdx.x * 2 + (tid >> 6)] = (float)__popcll(bal);
  }
  const int wid = wv, lane = tid & 63;
  const int col = lane & 15, kg = lane >> 4;
  bf16x8 a[4][2];
#pragma unroll
  for (int kk = 0; kk < 4; ++kk)
#pragma unroll
    for (int mb = 0; mb < 2; ++mb)
      a[kk][mb] = *reinterpret_cast<const bf16x8*>(wA + (size_t)((kk * 2 + mb) * 64 + lane) * 8);
  int voff0[4], voff1[4];
#pragma unroll
  for (int kk = 0; kk < 4; ++kk) {
    const int t0 = 8 * kk + 2 * kg, t1 = t0 + 1;
    const int r0 = (t0 < 27) ? t0 / 3 : 9, d0 = (t0 < 27) ? t0 % 3 : 0;
    const int r1 = (t1 < 27) ? t1 / 3 : 9, d1 = (t1 < 27) ? t1 % 3 : 0;
    voff0[kk] = r0 * RSTRIDE + 8 + d0 * 8 + col * 16 + wid * 512;
    voff1[kk] = r1 * RSTRIDE + 8 + d1 * 8 + col * 16 + wid * 512;
  }
  f32x4 acc[2][2];
#pragma unroll
  for (int m = 0; m < 2; ++m)
#pragma unroll
    for (int mb = 0; mb < 2; ++mb) acc[m][mb] = f32x4{0.f, 0.f, 0.f, 0.f};
#pragma unroll
  for (int m = 0; m < 2; ++m) {
#pragma unroll
    for (int kk = 0; kk < 4; ++kk) {
      const uint2 lo = *reinterpret_cast<const uint2*>(sfeat + voff0[kk] + m * 256);
      const uint2 hi = *reinterpret_cast<const uint2*>(sfeat + voff1[kk] + m * 256);
      union { uint2 q[2]; bf16x8 v; } bb;
      bb.q[0] = lo; bb.q[1] = hi;
#pragma unroll
      for (int mb = 0; mb < 2; ++mb)
        acc[m][mb] = __builtin_amdgcn_mfma_f32_16x16x32_bf16(a[kk][mb], bb.v, acc[m][mb], 0, 0, 0);
    }
  }
#pragma unroll
  for (int m = 0; m < 2; ++m) {
    const int vox = (wid * 2 + m) * 16 + col;
    u16* dst = x1p + ((size_t)row * WP1 + 1 + vox) * 32 + kg * 4;
#pragma unroll
    for (int mb = 0; mb < 2; ++mb) {
      uint2 pp;
      pp.x = pk2(acc[m][mb][0], acc[m][mb][1]);
      pp.y = pk2(acc[m][mb][2], acc[m][mb][3]);
      *reinterpret_cast<uint2*>(dst + mb * 16) = pp;
    }
  }
  __syncthreads();                      // smask visibility
  const float m0 = smask[(wid * 2 + 0) * 16 + col];
  const float m1 = smask[(wid * 2 + 1) * 16 + col];
  float sv[8], qv[8];
#pragma unroll
  for (int mb = 0; mb < 2; ++mb)
#pragma unroll
    for (int j = 0; j < 4; ++j) {
      const float a0 = acc[0][mb][j] * m0, a1 = acc[1][mb][j] * m1;
      sv[mb * 4 + j] = colred(a0 + a1);
      qv[mb * 4 + j] = colred(a0 * a0 + a1 * a1);
    }
  if (col == 0) {
    float* pp = part1 + ((size_t)blockIdx.x * 4 + wid) * 64;
#pragma unroll
    for (int mb = 0; mb < 2; ++mb)
#pragma unroll
      for (int j = 0; j < 4; ++j) {
        const int ch = mb * 16 + kg * 4 + j;
        pp[ch] = sv[mb * 4 + j];
        pp[32 + ch] = qv[mb * 4 + j];
      }
  }
}

// ---- mask3 = dilation of mask1, stride 2; per-block cnt3 ----
__global__ __launch_bounds__(256) void sl_mask3(const u8* __restrict__ mask1,
                                                u8* __restrict__ mask3,
                                                float* __restrict__ cnt3buf) {
  const int gid = blockIdx.x * 256 + threadIdx.x;
  if (gid >= NV3) return;
  const int b = gid / S3;
  const int s = gid - b * S3;
  const int z = s >> 12, y = (s >> 6) & 63, x = s & 63;
  bool any = false;
  for (int dz = 0; dz < 3; ++dz) {
    const int zi = 2 * z + dz - 1;
    if ((unsigned)zi >= (unsigned)D1) continue;
    for (int dy = 0; dy < 3; ++dy) {
      const int yi = 2 * y + dy - 1;
      if ((unsigned)yi >= (unsigned)H1) continue;
      for (int dx = 0; dx < 3; ++dx) {
        const int xi = 2 * x + dx - 1;
        if ((unsigned)xi >= (unsigned)W1) continue;
        if (mask1[((b * D1 + zi) * H1 + yi) * W1 + xi]) any = true;
      }
    }
  }
  mask3[gid] = any ? (u8)1 : (u8)0;
  const u64 bal = __ballot(any);
  if ((threadIdx.x & 63) == 0)
    cnt3buf[blockIdx.x * 4 + (threadIdx.x >> 6)] = (float)__popcll(bal);
}

// ---- in-place BN+ReLU+mask on padded buffer ----
template <int C>
__global__ __launch_bounds__(256) void sl_bnrelu(
    u16* __restrict__ x, const u8* __restrict__ mask,
    const float* __restrict__ sc, const float* __restrict__ sh,
    int nvox, int lw, int WPs, int pad) {
  const int v = blockIdx.x * 256 + threadIdx.x;
  if (v >= nvox) return;
  const int r = v >> lw;
  const int xx = v & ((1 << lw) - 1);
  const size_t pv = (size_t)r * WPs + pad + xx;
  u16* p = x + pv * C;
  if (mask[v]) {
#pragma unroll
    for (int g = 0; g < C / 8; ++g) {
      float f[8];
      bf8_unpack(reinterpret_cast<const uint4*>(p)[g], f);
      u16 o[8];
#pragma unroll
      for (int j = 0; j < 8; ++j)
        o[j] = f2b(fmaxf(fmaf(f[j], sc[g * 8 + j], sh[g * 8 + j]), 0.f));
      reinterpret_cast<uint4*>(p)[g] = *reinterpret_cast<uint4*>(o);
    }
  } else {
    const uint4 zz = {0u, 0u, 0u, 0u};
#pragma unroll
    for (int g = 0; g < C / 8; ++g) reinterpret_cast<uint4*>(p)[g] = zz;
  }
}

// ---- conv2 (stride 1): glds-staged, 32x32x16 MFMA; BN2 partials ----
// 4 waves = (mh = wid&1: out-ch half) x (nh = wid>>1: voxel half).
// Per tap: 2 MFMAs (kk = K16 halves), each fed by ONE ds_read_b128.
__global__ __launch_bounds__(256) void sl_conv2_mfma(
    const u16* __restrict__ y1p, const u16* __restrict__ wA, u16* __restrict__ x2p,
    const u8* __restrict__ mask1, const u16* __restrict__ zbuf,
    float* __restrict__ part2) {
  __shared__ __align__(16) u16 sB[9 * 4 * 66 * 8];    // 38,016 B (unchanged layout)
  const int tid = threadIdx.x;
  const int tile = xswz(blockIdx.x, NV1 / 64);
  const int xh = (tile & 1) * 64;
  const int rowid = tile >> 1;          // (b*D1+z)*H1 + y
  const int y = rowid & (H1 - 1);
  const int bz = rowid >> 7;
  const int z = bz % D1;
  const int wb = tid & ~63;             // wave base within block
#pragma unroll
  for (int it = 0; it < 10; ++it) {
    const int o = it * 256 + tid;
    if (o < 2376) {
      const int q = o / 66;             // r9*4 + g
      const int v = o - q * 66;
      const int g = q & 3, r9 = q >> 2;
      const int zi = z + r9 / 3 - 1;
      const int yi = y + r9 % 3 - 1;
      const u16* src;
      if ((unsigned)zi < (unsigned)D1 && (unsigned)yi < (unsigned)H1) {
        const int riq = (bz + r9 / 3 - 1) * H1 + yi;
        src = y1p + ((size_t)riq * WP1 + xh + v) * 32 + g * 8;
      } else {
        src = zbuf + (o & 63) * 8;
      }
      glds16(src, &sB[(size_t)(it * 256 + wb) * 8]);
    }
  }
  __syncthreads();
  const int wid = tid >> 6, lane = tid & 63;
  const int n = lane & 31, h = lane >> 5;
  const int mh = wid & 1, nh = wid >> 1;
  // A: elem offset = t*2048 + kk*1024 + mh*512 + lane*8
  const u16* aBase = wA + (size_t)mh * 512 + (size_t)lane * 8;
  // B: plane cg = kk*2 + h, voxel v = nh*32 + n + dx -> slot (r9*4+cg)*66 + v
  const u16* b0base = &sB[(size_t)((0 + h) * 66 + nh * 32 + n) * 8];
  const u16* b1base = &sB[(size_t)((2 + h) * 66 + nh * 32 + n) * 8];
  f32x16 acc = {0.f, 0.f, 0.f, 0.f, 0.f, 0.f, 0.f, 0.f,
                0.f, 0.f, 0.f, 0.f, 0.f, 0.f, 0.f, 0.f};
  bf16x8 ar0[2], ar1[2];                // [parity] for kk=0 / kk=1
  ar0[0] = *reinterpret_cast<const bf16x8*>(aBase);
  ar1[0] = *reinterpret_cast<const bf16x8*>(aBase + 1024);
  ar0[1] = *reinterpret_cast<const bf16x8*>(aBase + 2048);
  ar1[1] = *reinterpret_cast<const bf16x8*>(aBase + 3072);
#pragma unroll
  for (int t = 0; t < 27; ++t) {
    const bf16x8 a0 = ar0[t & 1];
    const bf16x8 a1 = ar1[t & 1];
    if (t + 2 < 27) {
      ar0[t & 1] = *reinterpret_cast<const bf16x8*>(aBase + (size_t)(t + 2) * 2048);
      ar1[t & 1] = *reinterpret_cast<const bf16x8*>(aBase + (size_t)(t + 2) * 2048 + 1024);
    }
    const int r9 = t / 3, dx = t % 3;
    const bf16x8 b0 = *reinterpret_cast<const bf16x8*>(b0base + (r9 * 264 + dx) * 8);
    const bf16x8 b1 = *reinterpret_cast<const bf16x8*>(b1base + (r9 * 264 + dx) * 8);
    acc = __builtin_amdgcn_mfma_f32_32x32x16_bf16(a0, b0, acc, 0, 0, 0);
    acc = __builtin_amdgcn_mfma_f32_32x32x16_bf16(a1, b1, acc, 0, 0, 0);
  }
  // C-write: col = n (voxel), row = (reg&3) + 8*(reg>>2) + 4*h (out-ch local)
  const int vox = xh + nh * 32 + n;
  u16* dst = x2p + ((size_t)rowid * WP1 + 1 + vox) * 64 + mh * 32 + h * 4;
#pragma unroll
  for (int g4 = 0; g4 < 4; ++g4) {
    uint2 pp;
    pp.x = pk2(acc[4 * g4 + 0], acc[4 * g4 + 1]);
    pp.y = pk2(acc[4 * g4 + 2], acc[4 * g4 + 3]);
    *reinterpret_cast<uint2*>(dst + g4 * 8) = pp;
  }
  // ---- BN2 partials (entry = tile*2 + nh; wave mh covers ch mh*32..+31) ----
  const float mk = (float)mask1[rowid * W1 + xh + nh * 32 + n];
  float* pp = part2 + (size_t)(tile * 2 + nh) * 128;
#pragma unroll
  for (int g4 = 0; g4 < 4; ++g4)
#pragma unroll
    for (int j = 0; j < 4; ++j) {
      const float av = acc[4 * g4 + j] * mk;
      const float s = colred32(av);
      const float q = colred32(av * av);
      if (n == 0) {
        const int ch = mh * 32 + 8 * g4 + j + 4 * h;
        pp[ch] = s;
        pp[64 + ch] = q;
      }
    }
}

// ---- conv3 (stride 2): per-(dz,dy) LDS-staged (slot-XOR); BN2+ReLU+mask at staging ----
__global__ __launch_bounds__(512) void sl_conv3_mfma(
    const u16* __restrict__ x2p, const u16* __restrict__ wA, u16* __restrict__ x3,
    const u8* __restrict__ mask1, const u8* __restrict__ mask3,
    const float* __restrict__ sc, const float* __restrict__ sh,
    float* __restrict__ part3) {
  __shared__ u16 sV[130 * 72];          // voxel stride 144B; 16B slots XOR'd by (sv>>1)&7
  const int tid = threadIdx.x;
  const int wid = tid >> 6, lane = tid & 63;
  const int col = lane & 15, kg = lane >> 4;
  const int tile = xswz(blockIdx.x, NV3 / 64);   // (b*D3+z)*H3 + yo
  const int yo = tile & (H3 - 1);
  const int r = tile >> 6;              // b*D3+z
  const int z = r % D3;
  const int b = r / D3;
  const int gch = (tid & 7) * 8;
  float scv[8], shv[8];
#pragma unroll
  for (int j = 0; j < 8; ++j) { scv[j] = sc[gch + j]; shv[j] = sh[gch + j]; }
  const int sxa = col & 7;              // (sv>>1)&7 for dx in {0,1}
  const int sxb = (col + 1) & 7;        // for dx == 2
  f32x4 acc[4];
#pragma unroll
  for (int nb = 0; nb < 4; ++nb) acc[nb] = f32x4{0.f, 0.f, 0.f, 0.f};
  for (int r9 = 0; r9 < 9; ++r9) {
    const int dz = r9 / 3, dy = r9 % 3;
    const int zi = 2 * z + dz - 1, yi = 2 * yo + dy - 1;
    if ((unsigned)zi >= (unsigned)D1 || (unsigned)yi >= (unsigned)H1) continue;  // uniform
    __syncthreads();                    // previous stage's reads done
    const int riq = (b * D1 + zi) * H1 + yi;
    const size_t rbase = (size_t)riq * WP1;
    for (int i = tid; i < 1040; i += 512) {
      const int sv = i >> 3, g = i & 7;
      const int slot = g ^ ((sv >> 1) & 7);
      const uint4 val = *reinterpret_cast<const uint4*>(x2p + (rbase + sv) * 64 + g * 8);
      const int x = sv - 1;
      u8 m = 0;
      if ((unsigned)x < (unsigned)W1) m = mask1[riq * W1 + x];
      uint4 out = {0u, 0u, 0u, 0u};
      if (m) {
        float f[8];
        bf8_unpack(val, f);
        u16 o[8];
#pragma unroll
        for (int j = 0; j < 8; ++j)
          o[j] = f2b(fmaxf(fmaf(f[j], scv[j], shv[j]), 0.f));
        out = *reinterpret_cast<uint4*>(o);
      }
      *reinterpret_cast<uint4*>(&sV[sv * 72 + slot * 8]) = out;
    }
    __syncthreads();
    bf16x8 af[3][2];
#pragma unroll
    for (int dx = 0; dx < 3; ++dx)
#pragma unroll
      for (int kk = 0; kk < 2; ++kk)
        af[dx][kk] = *reinterpret_cast<const bf16x8*>(
            wA + (size_t)(((r9 * 3 + dx) * 8 + wid) * 2 + kk) * 512 + lane * 8);
#pragma unroll
    for (int dx = 0; dx < 3; ++dx) {
      const int sx = (dx == 2) ? sxb : sxa;
      const int okg = 8 * (kg ^ (sx & 3));
      const int ok0 = okg + 32 * (sx >> 2);
      const int ok1 = okg + 32 * (1 ^ (sx >> 2));
#pragma unroll
      for (int nb = 0; nb < 4; ++nb) {
        const int svoff = (2 * (col + nb * 16) + dx) * 72;
        const bf16x8 b0 = *reinterpret_cast<const bf16x8*>(&sV[svoff + ok0]);
        const bf16x8 b1 = *reinterpret_cast<const bf16x8*>(&sV[svoff + ok1]);
        acc[nb] = __builtin_amdgcn_mfma_f32_16x16x32_bf16(af[dx][0], b0, acc[nb], 0, 0, 0);
        acc[nb] = __builtin_amdgcn_mfma_f32_16x16x32_bf16(af[dx][1], b1, acc[nb], 0, 0, 0);
      }
    }
  }
  u16* dst = x3 + ((size_t)tile * 64 + col) * 128 + wid * 16 + kg * 4;
#pragma unroll
  for (int nb = 0; nb < 4; ++nb) {
    uint2 pp;
    pp.x = pk2(acc[nb][0], acc[nb][1]);
    pp.y = pk2(acc[nb][2], acc[nb][3]);
    *reinterpret_cast<uint2*>(dst + (size_t)nb * 16 * 128) = pp;
  }
  float msk[4];
#pragma unroll
  for (int nb = 0; nb < 4; ++nb)
    msk[nb] = (float)mask3[tile * 64 + col + nb * 16];
  float* pp = part3 + (size_t)tile * 256;
#pragma unroll
  for (int j = 0; j < 4; ++j) {
    float s = 0.f, q = 0.f;
#pragma unroll
    for (int nb = 0; nb < 4; ++nb) {
      const float av = acc[nb][j] * msk[nb];
      s += av; q += av * av;
    }
    s = colred(s); q = colred(q);
    if (col == 0) {
      const int ch = wid * 16 + kg * 4 + j;
      pp[ch] = s;
      pp[128 + ch] = q;
    }
  }
}

// ---- finalize BN from per-block partials + per-block counts ----
__global__ __launch_bounds__(256) void sl_finalize_p(
    const float* __restrict__ part, int nt, int stride, int qoff,
    const float* __restrict__ cntbuf, int ncnt,
    const float* __restrict__ gamma, const float* __restrict__ beta,
    float* __restrict__ sc, float* __restrict__ sh) {
  __shared__ float ls[12];
  const int c = blockIdx.x;
  const int tid = threadIdx.x;
  float s = 0.f, q = 0.f, n = 0.f;
  for (int t = tid; t < nt; t += 256) {
    s += part[(size_t)t * stride + c];
    q += part[(size_t)t * stride + qoff + c];
  }
  for (int t = tid; t < ncnt; t += 256) n += cntbuf[t];
  for (int m = 1; m < 64; m <<= 1) {
    s += __shfl_xor(s, m); q += __shfl_xor(q, m); n += __shfl_xor(n, m);
  }
  if ((tid & 63) == 0) {
    ls[(tid >> 6) * 3] = s; ls[(tid >> 6) * 3 + 1] = q; ls[(tid >> 6) * 3 + 2] = n;
  }
  __syncthreads();
  if (tid == 0) {
    s = ls[0] + ls[3] + ls[6] + ls[9];
    q = ls[1] + ls[4] + ls[7] + ls[10];
    n = ls[2] + ls[5] + ls[8] + ls[11];
    const float m = s / n;
    const float var = fmaxf(q / n - m * m, 0.f);
    const float sca = gamma[c] * rsqrtf(var + 1e-5f);
    sc[c] = sca;
    sh[c] = beta[c] - m * sca;
  }
}

// ---- heads ----
__global__ __launch_bounds__(256) void sl_heads(
    const u16* __restrict__ x3, const u8* __restrict__ mask3,
    const float* __restrict__ sc, const float* __restrict__ sh,
    const float* __restrict__ Wc, const float* __restrict__ bc,
    const float* __restrict__ Wr, const float* __restrict__ br,
    float* __restrict__ out) {
  const int gid = blockIdx.x * 256 + threadIdx.x;
  const int b = gid / S3;
  const int s = gid - b * S3;
  float aC[3] = {0.f, 0.f, 0.f};
  float aR[7] = {0.f, 0.f, 0.f, 0.f, 0.f, 0.f, 0.f};
  if (mask3[gid]) {
#pragma unroll
    for (int k = 0; k < 3; ++k) aC[k] = bc[k];
#pragma unroll
    for (int k = 0; k < 7; ++k) aR[k] = br[k];
    const uint4* xp = reinterpret_cast<const uint4*>(x3 + (size_t)gid * C3);
#pragma unroll 2
    for (int g = 0; g < 16; ++g) {
      float f[8];
      bf8_unpack(xp[g], f);
#pragma unroll
      for (int j = 0; j < 8; ++j) {
        const int c = g * 8 + j;
        const float y = fmaxf(fmaf(f[j], sc[c], sh[c]), 0.f);
#pragma unroll
        for (int k = 0; k < 3; ++k) aC[k] = fmaf(y, Wc[k * C3 + c], aC[k]);
#pragma unroll
        for (int k = 0; k < 7; ++k) aR[k] = fmaf(y, Wr[k * C3 + c], aR[k]);
      }
    }
  }
#pragma unroll
  for (int k = 0; k < 3; ++k) out[(size_t)(b * 3 + k) * S3 + s] = aC[k];
  const size_t ob = (size_t)B * 3 * S3;
#pragma unroll
  for (int k = 0; k < 7; ++k) out[ob + (size_t)(b * 7 + k) * S3 + s] = aR[k];
}

extern "C" void kernel_launch(void* const* d_in, const int* in_sizes, int n_in,
                              void* d_out, int out_size, void* d_ws, size_t ws_size,
                              hipStream_t stream) {
  (void)in_sizes; (void)n_in; (void)out_size; (void)ws_size;
  const float* feat = (const float*)d_in[0];
  const int*   act  = (const int*)d_in[1];
  const float* w1 = (const float*)d_in[2];
  const float* g1 = (const float*)d_in[3];
  const float* b1 = (const float*)d_in[4];
  const float* w2 = (const float*)d_in[5];
  const float* g2 = (const float*)d_in[6];
  const float* b2 = (const float*)d_in[7];
  const float* w3 = (const float*)d_in[8];
  const float* g3 = (const float*)d_in[9];
  const float* b3 = (const float*)d_in[10];
  const float* Wc = (const float*)d_in[11];
  const float* bc = (const float*)d_in[12];
  const float* Wr = (const float*)d_in[13];
  const float* br = (const float*)d_in[14];
  float* out = (float*)d_out;

  char* ws = (char*)d_ws;
  size_t off = 0;
  auto take = [&](size_t bytes) {
    char* p = ws + off;
    off = (off + bytes + 255) & ~(size_t)255;
    return p;
  };
  u16* x1p = (u16*)take((size_t)PVOX1 * 32 * 2);   // 42.6 MB
  u16* x2p = (u16*)take((size_t)PVOX1 * 64 * 2);   // 85.2 MB
  u16* x3  = (u16*)take((size_t)NV3 * 128 * 2);    // 21.0 MB
  u16* mfeat = (u16*)take((size_t)B * S0 * 4 * 2); // 41.9 MB
  u8* aflag = (u8*)take((size_t)B * S0);           //  5.2 MB
  u8* mask1 = (u8*)take(NV1);
  u8* mask3 = (u8*)take(NV3);
  u16* wA1 = (u16*)take((size_t)512 * 8 * 2);
  u16* wA2 = (u16*)take((size_t)6912 * 8 * 2);               // 110 KB (32x32 A frags)
  u16* wA3 = (u16*)take((size_t)27 * 8 * 2 * 64 * 8 * 2);
  float* part1 = (float*)take((size_t)NROW1 * 4 * 64 * 4);        //  5.2 MB
  float* part2 = (float*)take((size_t)(NV1 / 64) * 2 * 128 * 4);  // 10.5 MB
  float* part3 = (float*)take((size_t)(NV3 / 64) * 256 * 4);      //  1.3 MB
  float* cnt1buf = (float*)take((size_t)NROW1 * 2 * 4);           // 40 KB
  float* cnt3buf = (float*)take((size_t)320 * 4 * 4);             //  5 KB
  u16* zbuf   = (u16*)take(1024);
  float* scales = (float*)take(448 * 4);

  float* sc1 = scales,       *sh1 = scales + 32;
  float* sc2 = scales + 64,  *sh2 = scales + 128;
  float* sc3 = scales + 192, *sh3 = scales + 320;

  hipMemsetAsync(zbuf, 0, 1024, stream);
  sl_repackA1<<<2, 256, 0, stream>>>(w1, wA1);
  sl_repackA2w<<<27, 256, 0, stream>>>(w2, wA2);
  sl_repackA3<<<108, 256, 0, stream>>>(w3, wA3);
  sl_prepack<<<B * S0 / 256, 256, 0, stream>>>(feat, act, mfeat, aflag);
  sl_halo1<<<(2 * NROW1 + 255) / 256, 256, 0, stream>>>(x1p);

  sl_conv1_mfma<<<NROW1, 256, 0, stream>>>(mfeat, aflag, wA1, zbuf, x1p, mask1,
                                           part1, cnt1buf);
  sl_mask3<<<(NV3 + 255) / 256, 256, 0, stream>>>(mask1, mask3, cnt3buf);
  sl_finalize_p<<<32, 256, 0, stream>>>(part1, NROW1 * 4, 64, 32,
                                        cnt1buf, NROW1 * 2, g1, b1, sc1, sh1);
  sl_bnrelu<32><<<(NV1 + 255) / 256, 256, 0, stream>>>(x1p, mask1, sc1, sh1, NV1, 7, WP1, 1);

  sl_conv2_mfma<<<NV1 / 64, 256, 0, stream>>>(x1p, wA2, x2p, mask1, zbuf, part2);
  sl_finalize_p<<<64, 256, 0, stream>>>(part2, (NV1 / 64) * 2, 128, 64,
                                        cnt1buf, NROW1 * 2, g2, b2, sc2, sh2);

  sl_conv3_mfma<<<NV3 / 64, 512, 0, stream>>>(x2p, wA3, x3, mask1, mask3,
                                              sc2, sh2, part3);
  sl_finalize_p<<<128, 256, 0, stream>>>(part3, NV3 / 64, 256, 128,
                                         cnt3buf, 320 * 4, g3, b3, sc3, sh3);

  sl_heads<<<NV3 / 256, 256, 0, stream>>>(x3, mask3, sc3, sh3, Wc, bc, Wr, br, out);
}

// Round 18
// 393.691 us; speedup vs baseline: 1.1272x; 1.1272x over previous
//
#include <hip/hip_runtime.h>
#include <hip/hip_bf16.h>

typedef unsigned short u16;
typedef unsigned char  u8;
typedef unsigned int   u32;
typedef unsigned long long u64;

typedef short bf16x8 __attribute__((ext_vector_type(8)));
typedef float f32x4  __attribute__((ext_vector_type(4)));

#define DEVI static __device__ __forceinline__

// ---- problem geometry ----
constexpr int B  = 2;
constexpr int C0 = 4,   D0 = 40, H0 = 256, W0 = 256;
constexpr int C1 = 32,  D1 = 20, H1 = 128, W1 = 128;
constexpr int C2 = 64;
constexpr int C3 = 128, D3 = 10, H3 = 64,  W3 = 64;
constexpr int S0 = D0 * H0 * W0;
constexpr int S1 = D1 * H1 * W1;             // 327,680
constexpr int S3 = D3 * H3 * W3;             // 40,960
constexpr int NV1 = B * S1;                  // 655,360
constexpr int NV3 = B * S3;                  // 81,920
constexpr int WP1 = W1 + 2;                  // padded x stride (130)
constexpr int NROW1 = B * D1 * H1;           // 5120 padded rows
constexpr int PVOX1 = NROW1 * WP1;           // 665,600 padded voxels
constexpr int RSTRIDE = 2080;                // conv1 staged row stride (bytes)

// ---- bf16 helpers ----
DEVI float b2f(u16 v) { return __uint_as_float(((u32)v) << 16); }
DEVI u16 f2b(float f) {
  u32 u = __float_as_uint(f);
  return (u16)((u + 0x7fffu + ((u >> 16) & 1u)) >> 16);
}
DEVI u32 pk2(float a, float b) { return (u32)f2b(a) | ((u32)f2b(b) << 16); }
DEVI void bf8_unpack(const uint4 u, float* f) {
  f[0] = b2f((u16)(u.x & 0xffffu)); f[1] = b2f((u16)(u.x >> 16));
  f[2] = b2f((u16)(u.y & 0xffffu)); f[3] = b2f((u16)(u.y >> 16));
  f[4] = b2f((u16)(u.z & 0xffffu)); f[5] = b2f((u16)(u.z >> 16));
  f[6] = b2f((u16)(u.w & 0xffffu)); f[7] = b2f((u16)(u.w >> 16));
}
DEVI float colred(float v) {   // sum over the 16 'col' lanes (lane bits 0..3)
  v += __shfl_xor(v, 1); v += __shfl_xor(v, 2);
  v += __shfl_xor(v, 4); v += __shfl_xor(v, 8);
  return v;
}
DEVI int xswz(int b, int n) {  // XCD-contiguous bijective swizzle (n % 8 == 0)
  const int c = n >> 3;
  return (b & 7) * c + (b >> 3);
}
DEVI void glds16(const void* g, void* l) {  // async global->LDS, 16B per lane
  __builtin_amdgcn_global_load_lds(
      (const __attribute__((address_space(1))) void*)g,
      (__attribute__((address_space(3))) void*)l, 16, 0, 0);
}

// ---- pre-pass: masked feature gather + f32->bf16 convert ----
__global__ __launch_bounds__(256) void sl_prepack(
    const float* __restrict__ feat, const int* __restrict__ act,
    u16* __restrict__ mfeat, u8* __restrict__ aflag) {
  const int i = blockIdx.x * 256 + threadIdx.x;   // < B*S0
  const int b = i / S0, sp = i - b * S0;
  u32 w0 = 0, w1 = 0; u8 fl = 0;
  if (act[i] == 0) {
    fl = 1;
    const size_t fb = (size_t)b * 4 * S0 + sp;
    w0 = pk2(feat[fb], feat[fb + S0]);
    w1 = pk2(feat[fb + 2 * (size_t)S0], feat[fb + 3 * (size_t)S0]);
  }
  *reinterpret_cast<uint2*>(mfeat + (size_t)i * 4) = uint2{w0, w1};
  aflag[i] = fl;
}

// ---- weight repack to MFMA A-fragment order (bf16), kk-major (conv2) ----
__global__ __launch_bounds__(256) void sl_repackA(const float* __restrict__ src,
                                                  u16* __restrict__ dst, int I, int O) {
  const int mbN = O / 16, kkN = I / 32;
  const int total = 27 * kkN * mbN * 64;
  const int idx = blockIdx.x * 256 + threadIdx.x;
  if (idx >= total) return;
  const int l = idx & 63;
  int r = idx >> 6;
  const int mb = r % mbN; r /= mbN;
  const int kk = r % kkN;
  const int t = r / kkN;
  const int o = mb * 16 + (l & 15);
  const int i0 = kk * 32 + (l >> 4) * 8;
  u16 f[8];
#pragma unroll
  for (int j = 0; j < 8; ++j) f[j] = f2b(src[((size_t)o * I + i0 + j) * 27 + t]);
  *reinterpret_cast<uint4*>(dst + (size_t)idx * 8) = *reinterpret_cast<uint4*>(f);
}

// ---- weight repack, mb-major (conv3) ----
__global__ __launch_bounds__(256) void sl_repackA3(const float* __restrict__ src,
                                                   u16* __restrict__ dst) {
  const int total = 27 * 8 * 2 * 64;
  const int idx = blockIdx.x * 256 + threadIdx.x;
  if (idx >= total) return;
  const int l = idx & 63;
  int r = idx >> 6;
  const int kk = r % 2; r /= 2;
  const int mb = r % 8;
  const int t = r / 8;
  const int o = mb * 16 + (l & 15);
  const int i0 = kk * 32 + (l >> 4) * 8;
  u16 f[8];
#pragma unroll
  for (int j = 0; j < 8; ++j) f[j] = f2b(src[((size_t)o * 64 + i0 + j) * 27 + t]);
  *reinterpret_cast<uint4*>(dst + (size_t)idx * 8) = *reinterpret_cast<uint4*>(f);
}

// ---- conv1 weight repack: K = tap*4 + ic, padded to 128 ----
__global__ __launch_bounds__(256) void sl_repackA1(const float* __restrict__ src,
                                                   u16* __restrict__ dst) {
  const int idx = blockIdx.x * 256 + threadIdx.x;   // < 512
  if (idx >= 512) return;
  const int l = idx & 63;
  int r = idx >> 6;
  const int mb = r % 2;
  const int kk = r / 2;
  const int o = mb * 16 + (l & 15);
  u16 f[8];
#pragma unroll
  for (int j = 0; j < 8; ++j) {
    const int k = kk * 32 + (l >> 4) * 8 + j;
    const int t = k >> 2, ic = k & 3;
    f[j] = (t < 27) ? f2b(src[((size_t)o * 4 + ic) * 27 + t]) : (u16)0;
  }
  *reinterpret_cast<uint4*>(dst + (size_t)idx * 8) = *reinterpret_cast<uint4*>(f);
}

// ---- zero the x-halo columns of x1p ----
__global__ __launch_bounds__(256) void sl_halo1(u16* __restrict__ x1p) {
  const int i = blockIdx.x * 256 + threadIdx.x;
  if (i >= 2 * NROW1) return;
  const int r = i >> 1, side = i & 1;
  const size_t p = (size_t)r * WP1 + side * (WP1 - 1);
  const uint4 z4 = {0u, 0u, 0u, 0u};
  uint4* p1 = reinterpret_cast<uint4*>(x1p + p * 32);
#pragma unroll
  for (int j = 0; j < 4; ++j) p1[j] = z4;
}

// ---- conv1 via MFMA: glds-staged im2col; mask1 + BN1 partials; no atomics ----
__global__ __launch_bounds__(256) void sl_conv1_mfma(
    const u16* __restrict__ mfeat, const u8* __restrict__ aflag,
    const u16* __restrict__ wA, const u16* __restrict__ zbuf,
    u16* __restrict__ x1p, u8* __restrict__ mask1,
    float* __restrict__ part1, float* __restrict__ cnt1buf) {
  __shared__ __align__(16) char sfeat[10 * RSTRIDE];   // 20,800 B
  __shared__ __align__(16) u8 sflagP[9 * 256];         //  2,304 B
  __shared__ float smask[128];
  const int tid = threadIdx.x;
  const int row = xswz(blockIdx.x, NROW1);   // (b*D1+z)*H1 + y
  const int y = row & (H1 - 1);
  const int bz = row >> 7;
  const int z = bz % D1;
  const int b = bz / D1;
  const int wv = tid >> 6, ln = tid & 63;
  const uint4 z4 = {0u, 0u, 0u, 0u};
  if (tid < 18) {
    const int r = tid >> 1, side = tid & 1;
    *reinterpret_cast<uint4*>(&sfeat[r * RSTRIDE + side * 2064]) = z4;
  } else if (tid < 148) {
    const int idx = tid - 18;
    *reinterpret_cast<uint4*>(&sfeat[9 * RSTRIDE + idx * 16]) = z4;
  }
#pragma unroll
  for (int i = 0; i < 5; ++i) {
    const int h = i * 4 + wv;
    if (h < 18) {
      const int r9 = h >> 1, half = h & 1;
      const int zi = 2 * z + r9 / 3 - 1;
      const int yi = 2 * y + r9 % 3 - 1;
      const u16* src;
      if ((unsigned)zi < (unsigned)D0 && (unsigned)yi < (unsigned)H0)
        src = mfeat + ((size_t)(b * S0 + (zi * H0 + yi) * W0 + half * 128) + 2 * ln) * 4;
      else
        src = zbuf + ln * 8;
      glds16(src, &sfeat[r9 * RSTRIDE + 16 + half * 1024]);
    }
  }
  {
    const int r9 = tid >> 4, k = tid & 15;
    if (r9 < 9) {
      const int zi = 2 * z + r9 / 3 - 1;
      const int yi = 2 * y + r9 % 3 - 1;
      const void* src;
      if ((unsigned)zi < (unsigned)D0 && (unsigned)yi < (unsigned)H0)
        src = aflag + b * S0 + (zi * H0 + yi) * W0 + k * 16;
      else
        src = (const u8*)zbuf + ln * 16;
      glds16(src, &sflagP[wv * 1024]);
    }
  }
  __syncthreads();
  if (tid < 128) {
    bool any = false;
#pragma unroll
    for (int r9 = 0; r9 < 9; ++r9)
#pragma unroll
      for (int dx = 0; dx < 3; ++dx) {
        const int xi = 2 * tid + dx - 1;
        any |= (xi >= 0) && (sflagP[r9 * 256 + xi] != 0);
      }
    mask1[row * W1 + tid] = any ? (u8)1 : (u8)0;
    smask[tid] = any ? 1.f : 0.f;
    const u64 bal = __ballot(any);
    if ((tid & 63) == 0)
      cnt1buf[blockIdx.x * 2 + (tid >> 6)] = (float)__popcll(bal);
  }
  const int wid = wv, lane = tid & 63;
  const int col = lane & 15, kg = lane >> 4;
  bf16x8 a[4][2];
#pragma unroll
  for (int kk = 0; kk < 4; ++kk)
#pragma unroll
    for (int mb = 0; mb < 2; ++mb)
      a[kk][mb] = *reinterpret_cast<const bf16x8*>(wA + (size_t)((kk * 2 + mb) * 64 + lane) * 8);
  int voff0[4], voff1[4];
#pragma unroll
  for (int kk = 0; kk < 4; ++kk) {
    const int t0 = 8 * kk + 2 * kg, t1 = t0 + 1;
    const int r0 = (t0 < 27) ? t0 / 3 : 9, d0 = (t0 < 27) ? t0 % 3 : 0;
    const int r1 = (t1 < 27) ? t1 / 3 : 9, d1 = (t1 < 27) ? t1 % 3 : 0;
    voff0[kk] = r0 * RSTRIDE + 8 + d0 * 8 + col * 16 + wid * 512;
    voff1[kk] = r1 * RSTRIDE + 8 + d1 * 8 + col * 16 + wid * 512;
  }
  f32x4 acc[2][2];
#pragma unroll
  for (int m = 0; m < 2; ++m)
#pragma unroll
    for (int mb = 0; mb < 2; ++mb) acc[m][mb] = f32x4{0.f, 0.f, 0.f, 0.f};
#pragma unroll
  for (int m = 0; m < 2; ++m) {
#pragma unroll
    for (int kk = 0; kk < 4; ++kk) {
      const uint2 lo = *reinterpret_cast<const uint2*>(sfeat + voff0[kk] + m * 256);
      const uint2 hi = *reinterpret_cast<const uint2*>(sfeat + voff1[kk] + m * 256);
      union { uint2 q[2]; bf16x8 v; } bb;
      bb.q[0] = lo; bb.q[1] = hi;
#pragma unroll
      for (int mb = 0; mb < 2; ++mb)
        acc[m][mb] = __builtin_amdgcn_mfma_f32_16x16x32_bf16(a[kk][mb], bb.v, acc[m][mb], 0, 0, 0);
    }
  }
#pragma unroll
  for (int m = 0; m < 2; ++m) {
    const int vox = (wid * 2 + m) * 16 + col;
    u16* dst = x1p + ((size_t)row * WP1 + 1 + vox) * 32 + kg * 4;
#pragma unroll
    for (int mb = 0; mb < 2; ++mb) {
      uint2 pp;
      pp.x = pk2(acc[m][mb][0], acc[m][mb][1]);
      pp.y = pk2(acc[m][mb][2], acc[m][mb][3]);
      *reinterpret_cast<uint2*>(dst + mb * 16) = pp;
    }
  }
  __syncthreads();                      // smask visibility
  const float m0 = smask[(wid * 2 + 0) * 16 + col];
  const float m1 = smask[(wid * 2 + 1) * 16 + col];
  float sv[8], qv[8];
#pragma unroll
  for (int mb = 0; mb < 2; ++mb)
#pragma unroll
    for (int j = 0; j < 4; ++j) {
      const float a0 = acc[0][mb][j] * m0, a1 = acc[1][mb][j] * m1;
      sv[mb * 4 + j] = colred(a0 + a1);
      qv[mb * 4 + j] = colred(a0 * a0 + a1 * a1);
    }
  if (col == 0) {
    float* pp = part1 + ((size_t)blockIdx.x * 4 + wid) * 64;
#pragma unroll
    for (int mb = 0; mb < 2; ++mb)
#pragma unroll
      for (int j = 0; j < 4; ++j) {
        const int ch = mb * 16 + kg * 4 + j;
        pp[ch] = sv[mb * 4 + j];
        pp[32 + ch] = qv[mb * 4 + j];
      }
  }
}

// ---- mask3 = dilation of mask1, stride 2; per-block cnt3 ----
__global__ __launch_bounds__(256) void sl_mask3(const u8* __restrict__ mask1,
                                                u8* __restrict__ mask3,
                                                float* __restrict__ cnt3buf) {
  const int gid = blockIdx.x * 256 + threadIdx.x;
  if (gid >= NV3) return;
  const int b = gid / S3;
  const int s = gid - b * S3;
  const int z = s >> 12, y = (s >> 6) & 63, x = s & 63;
  bool any = false;
  for (int dz = 0; dz < 3; ++dz) {
    const int zi = 2 * z + dz - 1;
    if ((unsigned)zi >= (unsigned)D1) continue;
    for (int dy = 0; dy < 3; ++dy) {
      const int yi = 2 * y + dy - 1;
      if ((unsigned)yi >= (unsigned)H1) continue;
      for (int dx = 0; dx < 3; ++dx) {
        const int xi = 2 * x + dx - 1;
        if ((unsigned)xi >= (unsigned)W1) continue;
        if (mask1[((b * D1 + zi) * H1 + yi) * W1 + xi]) any = true;
      }
    }
  }
  mask3[gid] = any ? (u8)1 : (u8)0;
  const u64 bal = __ballot(any);
  if ((threadIdx.x & 63) == 0)
    cnt3buf[blockIdx.x * 4 + (threadIdx.x >> 6)] = (float)__popcll(bal);
}

// ---- in-place BN+ReLU+mask on padded buffer ----
template <int C>
__global__ __launch_bounds__(256) void sl_bnrelu(
    u16* __restrict__ x, const u8* __restrict__ mask,
    const float* __restrict__ sc, const float* __restrict__ sh,
    int nvox, int lw, int WPs, int pad) {
  const int v = blockIdx.x * 256 + threadIdx.x;
  if (v >= nvox) return;
  const int r = v >> lw;
  const int xx = v & ((1 << lw) - 1);
  const size_t pv = (size_t)r * WPs + pad + xx;
  u16* p = x + pv * C;
  if (mask[v]) {
#pragma unroll
    for (int g = 0; g < C / 8; ++g) {
      float f[8];
      bf8_unpack(reinterpret_cast<const uint4*>(p)[g], f);
      u16 o[8];
#pragma unroll
      for (int j = 0; j < 8; ++j)
        o[j] = f2b(fmaxf(fmaf(f[j], sc[g * 8 + j], sh[g * 8 + j]), 0.f));
      reinterpret_cast<uint4*>(p)[g] = *reinterpret_cast<uint4*>(o);
    }
  } else {
    const uint4 zz = {0u, 0u, 0u, 0u};
#pragma unroll
    for (int g = 0; g < C / 8; ++g) reinterpret_cast<uint4*>(p)[g] = zz;
  }
}

// ---- conv2 (stride 1): glds-staged implicit GEMM; BN2 partials (best known) ----
__global__ __launch_bounds__(256) void sl_conv2_mfma(
    const u16* __restrict__ y1p, const u16* __restrict__ wA, u16* __restrict__ x2p,
    const u8* __restrict__ mask1, const u16* __restrict__ zbuf,
    float* __restrict__ part2) {
  __shared__ __align__(16) u16 sB[9 * 4 * 66 * 8];    // 38,016 B
  const int tid = threadIdx.x;
  const int tile = xswz(blockIdx.x, NV1 / 64);
  const int xh = (tile & 1) * 64;
  const int rowid = tile >> 1;          // (b*D1+z)*H1 + y
  const int y = rowid & (H1 - 1);
  const int bz = rowid >> 7;
  const int z = bz % D1;
  const int wb = tid & ~63;             // wave base within block
#pragma unroll
  for (int it = 0; it < 10; ++it) {
    const int o = it * 256 + tid;
    if (o < 2376) {
      const int q = o / 66;             // r9*4 + g
      const int v = o - q * 66;
      const int g = q & 3, r9 = q >> 2;
      const int zi = z + r9 / 3 - 1;
      const int yi = y + r9 % 3 - 1;
      const u16* src;
      if ((unsigned)zi < (unsigned)D1 && (unsigned)yi < (unsigned)H1) {
        const int riq = (bz + r9 / 3 - 1) * H1 + yi;
        src = y1p + ((size_t)riq * WP1 + xh + v) * 32 + g * 8;
      } else {
        src = zbuf + (o & 63) * 8;
      }
      glds16(src, &sB[(size_t)(it * 256 + wb) * 8]);
    }
  }
  __syncthreads();
  const int wid = tid >> 6, lane = tid & 63;
  const int col = lane & 15, kg = lane >> 4;
  const u16* sbase = &sB[(kg * 66 + col) * 8];
  const u16* aBase = wA + ((size_t)wid * 64 + lane) * 8;   // t-stride = 2048 elem
  f32x4 acc[4];
#pragma unroll
  for (int nb = 0; nb < 4; ++nb) acc[nb] = f32x4{0.f, 0.f, 0.f, 0.f};
  bf16x8 areg[2];
  areg[0] = *reinterpret_cast<const bf16x8*>(aBase);
  areg[1] = *reinterpret_cast<const bf16x8*>(aBase + 2048);
#pragma unroll
  for (int t = 0; t < 27; ++t) {
    const bf16x8 aC = areg[t & 1];
    if (t + 2 < 27)
      areg[t & 1] = *reinterpret_cast<const bf16x8*>(aBase + (size_t)(t + 2) * 2048);
    const int r9 = t / 3, dx = t % 3;
#pragma unroll
    for (int nb = 0; nb < 4; ++nb) {
      const bf16x8 bfr = *reinterpret_cast<const bf16x8*>(
          sbase + (r9 * 264 + nb * 16 + dx) * 8);
      acc[nb] = __builtin_amdgcn_mfma_f32_16x16x32_bf16(aC, bfr, acc[nb], 0, 0, 0);
    }
  }
#pragma unroll
  for (int nb = 0; nb < 4; ++nb) {
    u16* dst = x2p + ((size_t)rowid * WP1 + 1 + xh + col + nb * 16) * 64 + wid * 16 + kg * 4;
    uint2 pp;
    pp.x = pk2(acc[nb][0], acc[nb][1]);
    pp.y = pk2(acc[nb][2], acc[nb][3]);
    *reinterpret_cast<uint2*>(dst) = pp;
  }
  // ---- BN2 partials ----
  float msk[4];
#pragma unroll
  for (int nb = 0; nb < 4; ++nb)
    msk[nb] = (float)mask1[rowid * W1 + xh + col + nb * 16];
  float* pp = part2 + (size_t)tile * 128;
#pragma unroll
  for (int j = 0; j < 4; ++j) {
    float s = 0.f, q = 0.f;
#pragma unroll
    for (int nb = 0; nb < 4; ++nb) {
      const float av = acc[nb][j] * msk[nb];
      s += av; q += av * av;
    }
    s = colred(s); q = colred(q);
    if (col == 0) {
      const int ch = wid * 16 + kg * 4 + j;
      pp[ch] = s;
      pp[64 + ch] = q;
    }
  }
}

// ---- conv3 (stride 2): per-(dz,dy) LDS-staged (slot-XOR); BN2+ReLU+mask at staging ----
__global__ __launch_bounds__(512) void sl_conv3_mfma(
    const u16* __restrict__ x2p, const u16* __restrict__ wA, u16* __restrict__ x3,
    const u8* __restrict__ mask1, const u8* __restrict__ mask3,
    const float* __restrict__ sc, const float* __restrict__ sh,
    float* __restrict__ part3) {
  __shared__ u16 sV[130 * 72];          // voxel stride 144B; 16B slots XOR'd by (sv>>1)&7
  const int tid = threadIdx.x;
  const int wid = tid >> 6, lane = tid & 63;
  const int col = lane & 15, kg = lane >> 4;
  const int tile = xswz(blockIdx.x, NV3 / 64);   // (b*D3+z)*H3 + yo
  const int yo = tile & (H3 - 1);
  const int r = tile >> 6;              // b*D3+z
  const int z = r % D3;
  const int b = r / D3;
  const int gch = (tid & 7) * 8;
  float scv[8], shv[8];
#pragma unroll
  for (int j = 0; j < 8; ++j) { scv[j] = sc[gch + j]; shv[j] = sh[gch + j]; }
  const int sxa = col & 7;              // (sv>>1)&7 for dx in {0,1}
  const int sxb = (col + 1) & 7;        // for dx == 2
  f32x4 acc[4];
#pragma unroll
  for (int nb = 0; nb < 4; ++nb) acc[nb] = f32x4{0.f, 0.f, 0.f, 0.f};
  for (int r9 = 0; r9 < 9; ++r9) {
    const int dz = r9 / 3, dy = r9 % 3;
    const int zi = 2 * z + dz - 1, yi = 2 * yo + dy - 1;
    if ((unsigned)zi >= (unsigned)D1 || (unsigned)yi >= (unsigned)H1) continue;  // uniform
    __syncthreads();                    // previous stage's reads done
    const int riq = (b * D1 + zi) * H1 + yi;
    const size_t rbase = (size_t)riq * WP1;
    for (int i = tid; i < 1040; i += 512) {
      const int sv = i >> 3, g = i & 7;
      const int slot = g ^ ((sv >> 1) & 7);
      const uint4 val = *reinterpret_cast<const uint4*>(x2p + (rbase + sv) * 64 + g * 8);
      const int x = sv - 1;
      u8 m = 0;
      if ((unsigned)x < (unsigned)W1) m = mask1[riq * W1 + x];
      uint4 out = {0u, 0u, 0u, 0u};
      if (m) {
        float f[8];
        bf8_unpack(val, f);
        u16 o[8];
#pragma unroll
        for (int j = 0; j < 8; ++j)
          o[j] = f2b(fmaxf(fmaf(f[j], scv[j], shv[j]), 0.f));
        out = *reinterpret_cast<uint4*>(o);
      }
      *reinterpret_cast<uint4*>(&sV[sv * 72 + slot * 8]) = out;
    }
    __syncthreads();
    bf16x8 af[3][2];
#pragma unroll
    for (int dx = 0; dx < 3; ++dx)
#pragma unroll
      for (int kk = 0; kk < 2; ++kk)
        af[dx][kk] = *reinterpret_cast<const bf16x8*>(
            wA + (size_t)(((r9 * 3 + dx) * 8 + wid) * 2 + kk) * 512 + lane * 8);
#pragma unroll
    for (int dx = 0; dx < 3; ++dx) {
      const int sx = (dx == 2) ? sxb : sxa;
      const int okg = 8 * (kg ^ (sx & 3));
      const int ok0 = okg + 32 * (sx >> 2);
      const int ok1 = okg + 32 * (1 ^ (sx >> 2));
#pragma unroll
      for (int nb = 0; nb < 4; ++nb) {
        const int svoff = (2 * (col + nb * 16) + dx) * 72;
        const bf16x8 b0 = *reinterpret_cast<const bf16x8*>(&sV[svoff + ok0]);
        const bf16x8 b1 = *reinterpret_cast<const bf16x8*>(&sV[svoff + ok1]);
        acc[nb] = __builtin_amdgcn_mfma_f32_16x16x32_bf16(af[dx][0], b0, acc[nb], 0, 0, 0);
        acc[nb] = __builtin_amdgcn_mfma_f32_16x16x32_bf16(af[dx][1], b1, acc[nb], 0, 0, 0);
      }
    }
  }
  u16* dst = x3 + ((size_t)tile * 64 + col) * 128 + wid * 16 + kg * 4;
#pragma unroll
  for (int nb = 0; nb < 4; ++nb) {
    uint2 pp;
    pp.x = pk2(acc[nb][0], acc[nb][1]);
    pp.y = pk2(acc[nb][2], acc[nb][3]);
    *reinterpret_cast<uint2*>(dst + (size_t)nb * 16 * 128) = pp;
  }
  float msk[4];
#pragma unroll
  for (int nb = 0; nb < 4; ++nb)
    msk[nb] = (float)mask3[tile * 64 + col + nb * 16];
  float* pp = part3 + (size_t)tile * 256;
#pragma unroll
  for (int j = 0; j < 4; ++j) {
    float s = 0.f, q = 0.f;
#pragma unroll
    for (int nb = 0; nb < 4; ++nb) {
      const float av = acc[nb][j] * msk[nb];
      s += av; q += av * av;
    }
    s = colred(s); q = colred(q);
    if (col == 0) {
      const int ch = wid * 16 + kg * 4 + j;
      pp[ch] = s;
      pp[128 + ch] = q;
    }
  }
}

// ---- finalize BN from per-block partials + per-block counts ----
__global__ __launch_bounds__(256) void sl_finalize_p(
    const float* __restrict__ part, int nt, int stride, int qoff,
    const float* __restrict__ cntbuf, int ncnt,
    const float* __restrict__ gamma, const float* __restrict__ beta,
    float* __restrict__ sc, float* __restrict__ sh) {
  __shared__ float ls[12];
  const int c = blockIdx.x;
  const int tid = threadIdx.x;
  float s = 0.f, q = 0.f, n = 0.f;
  for (int t = tid; t < nt; t += 256) {
    s += part[(size_t)t * stride + c];
    q += part[(size_t)t * stride + qoff + c];
  }
  for (int t = tid; t < ncnt; t += 256) n += cntbuf[t];
  for (int m = 1; m < 64; m <<= 1) {
    s += __shfl_xor(s, m); q += __shfl_xor(q, m); n += __shfl_xor(n, m);
  }
  if ((tid & 63) == 0) {
    ls[(tid >> 6) * 3] = s; ls[(tid >> 6) * 3 + 1] = q; ls[(tid >> 6) * 3 + 2] = n;
  }
  __syncthreads();
  if (tid == 0) {
    s = ls[0] + ls[3] + ls[6] + ls[9];
    q = ls[1] + ls[4] + ls[7] + ls[10];
    n = ls[2] + ls[5] + ls[8] + ls[11];
    const float m = s / n;
    const float var = fmaxf(q / n - m * m, 0.f);
    const float sca = gamma[c] * rsqrtf(var + 1e-5f);
    sc[c] = sca;
    sh[c] = beta[c] - m * sca;
  }
}

// ---- heads ----
__global__ __launch_bounds__(256) void sl_heads(
    const u16* __restrict__ x3, const u8* __restrict__ mask3,
    const float* __restrict__ sc, const float* __restrict__ sh,
    const float* __restrict__ Wc, const float* __restrict__ bc,
    const float* __restrict__ Wr, const float* __restrict__ br,
    float* __restrict__ out) {
  const int gid = blockIdx.x * 256 + threadIdx.x;
  const int b = gid / S3;
  const int s = gid - b * S3;
  float aC[3] = {0.f, 0.f, 0.f};
  float aR[7] = {0.f, 0.f, 0.f, 0.f, 0.f, 0.f, 0.f};
  if (mask3[gid]) {
#pragma unroll
    for (int k = 0; k < 3; ++k) aC[k] = bc[k];
#pragma unroll
    for (int k = 0; k < 7; ++k) aR[k] = br[k];
    const uint4* xp = reinterpret_cast<const uint4*>(x3 + (size_t)gid * C3);
#pragma unroll 2
    for (int g = 0; g < 16; ++g) {
      float f[8];
      bf8_unpack(xp[g], f);
#pragma unroll
      for (int j = 0; j < 8; ++j) {
        const int c = g * 8 + j;
        const float y = fmaxf(fmaf(f[j], sc[c], sh[c]), 0.f);
#pragma unroll
        for (int k = 0; k < 3; ++k) aC[k] = fmaf(y, Wc[k * C3 + c], aC[k]);
#pragma unroll
        for (int k = 0; k < 7; ++k) aR[k] = fmaf(y, Wr[k * C3 + c], aR[k]);
      }
    }
  }
#pragma unroll
  for (int k = 0; k < 3; ++k) out[(size_t)(b * 3 + k) * S3 + s] = aC[k];
  const size_t ob = (size_t)B * 3 * S3;
#pragma unroll
  for (int k = 0; k < 7; ++k) out[ob + (size_t)(b * 7 + k) * S3 + s] = aR[k];
}

extern "C" void kernel_launch(void* const* d_in, const int* in_sizes, int n_in,
                              void* d_out, int out_size, void* d_ws, size_t ws_size,
                              hipStream_t stream) {
  (void)in_sizes; (void)n_in; (void)out_size; (void)ws_size;
  const float* feat = (const float*)d_in[0];
  const int*   act  = (const int*)d_in[1];
  const float* w1 = (const float*)d_in[2];
  const float* g1 = (const float*)d_in[3];
  const float* b1 = (const float*)d_in[4];
  const float* w2 = (const float*)d_in[5];
  const float* g2 = (const float*)d_in[6];
  const float* b2 = (const float*)d_in[7];
  const float* w3 = (const float*)d_in[8];
  const float* g3 = (const float*)d_in[9];
  const float* b3 = (const float*)d_in[10];
  const float* Wc = (const float*)d_in[11];
  const float* bc = (const float*)d_in[12];
  const float* Wr = (const float*)d_in[13];
  const float* br = (const float*)d_in[14];
  float* out = (float*)d_out;

  char* ws = (char*)d_ws;
  size_t off = 0;
  auto take = [&](size_t bytes) {
    char* p = ws + off;
    off = (off + bytes + 255) & ~(size_t)255;
    return p;
  };
  u16* x1p = (u16*)take((size_t)PVOX1 * 32 * 2);   // 42.6 MB
  u16* x2p = (u16*)take((size_t)PVOX1 * 64 * 2);   // 85.2 MB
  u16* x3  = (u16*)take((size_t)NV3 * 128 * 2);    // 21.0 MB
  u16* mfeat = (u16*)take((size_t)B * S0 * 4 * 2); // 41.9 MB
  u8* aflag = (u8*)take((size_t)B * S0);           //  5.2 MB
  u8* mask1 = (u8*)take(NV1);
  u8* mask3 = (u8*)take(NV3);
  u16* wA1 = (u16*)take((size_t)512 * 8 * 2);
  u16* wA2 = (u16*)take((size_t)27 * 4 * 64 * 8 * 2);
  u16* wA3 = (u16*)take((size_t)27 * 8 * 2 * 64 * 8 * 2);
  float* part1 = (float*)take((size_t)NROW1 * 4 * 64 * 4);   // 5.2 MB
  float* part2 = (float*)take((size_t)(NV1 / 64) * 128 * 4); // 5.2 MB
  float* part3 = (float*)take((size_t)(NV3 / 64) * 256 * 4); // 1.3 MB
  float* cnt1buf = (float*)take((size_t)NROW1 * 2 * 4);      // 40 KB
  float* cnt3buf = (float*)take((size_t)320 * 4 * 4);        //  5 KB
  u16* zbuf   = (u16*)take(1024);
  float* scales = (float*)take(448 * 4);

  float* sc1 = scales,       *sh1 = scales + 32;
  float* sc2 = scales + 64,  *sh2 = scales + 128;
  float* sc3 = scales + 192, *sh3 = scales + 320;

  hipMemsetAsync(zbuf, 0, 1024, stream);
  sl_repackA1<<<2, 256, 0, stream>>>(w1, wA1);
  sl_repackA<<<27, 256, 0, stream>>>(w2, wA2, 32, 64);
  sl_repackA3<<<108, 256, 0, stream>>>(w3, wA3);
  sl_prepack<<<B * S0 / 256, 256, 0, stream>>>(feat, act, mfeat, aflag);
  sl_halo1<<<(2 * NROW1 + 255) / 256, 256, 0, stream>>>(x1p);

  sl_conv1_mfma<<<NROW1, 256, 0, stream>>>(mfeat, aflag, wA1, zbuf, x1p, mask1,
                                           part1, cnt1buf);
  sl_mask3<<<(NV3 + 255) / 256, 256, 0, stream>>>(mask1, mask3, cnt3buf);
  sl_finalize_p<<<32, 256, 0, stream>>>(part1, NROW1 * 4, 64, 32,
                                        cnt1buf, NROW1 * 2, g1, b1, sc1, sh1);
  sl_bnrelu<32><<<(NV1 + 255) / 256, 256, 0, stream>>>(x1p, mask1, sc1, sh1, NV1, 7, WP1, 1);

  sl_conv2_mfma<<<NV1 / 64, 256, 0, stream>>>(x1p, wA2, x2p, mask1, zbuf, part2);
  sl_finalize_p<<<64, 256, 0, stream>>>(part2, NV1 / 64, 128, 64,
                                        cnt1buf, NROW1 * 2, g2, b2, sc2, sh2);

  sl_conv3_mfma<<<NV3 / 64, 512, 0, stream>>>(x2p, wA3, x3, mask1, mask3,
                                              sc2, sh2, part3);
  sl_finalize_p<<<128, 256, 0, stream>>>(part3, NV3 / 64, 256, 128,
                                         cnt3buf, 320 * 4, g3, b3, sc3, sh3);

  sl_heads<<<NV3 / 256, 256, 0, stream>>>(x3, mask3, sc3, sh3, Wc, bc, Wr, br, out);
}